// Round 4
// baseline (288.937 us; speedup 1.0000x reference)
//
#include <hip/hip_runtime.h>

// GNN_44306882625625: 2-layer SAGEConv + node-sum readout, fp32.
// Layer-2 collapsed algebraically: out = S_hw @ W2l^T + N*b2 + S_h @ W2r^T
// with S_h = sum_n h[n], S_hw = sum_n wsum[n]*h[n],
// wsum[n] = sum_{edges e: src=n} 1/max(cnt[dst_e],1).
// Layer-1: CSR build (hist/scan/scatter), then ONE fused kernel:
// gather neighbor-mean into LDS (lane=feature) -> barrier -> transform
// (lane=hidden unit, LDS broadcast reads, weights in VGPRs) -> register
// accumulation of S_h/S_hw. mean1 never touches HBM.

constexpr int N = 50000;   // nodes
constexpr int F = 64;      // in feat
constexpr int H = 128;     // hidden
constexpr int O = 10;      // out
constexpr int E = 800000;  // edges

constexpr int SCAN_B = 256;
constexpr int NBLK_SCAN = (N + SCAN_B - 1) / SCAN_B;  // 196

constexpr int TN = 16;           // nodes per tile in fused kernel
constexpr int NT = N / TN;       // 3125 exactly
constexpr int NWG_F = 1024;      // fused-kernel grid

// workspace layout (4-byte element offsets)
constexpr int CNT_OFF  = 0;                 // N ints   : in-degree
constexpr int WSUM_OFF = CNT_OFF + N;       // N floats : wsum
constexpr int WOFF_OFF = WSUM_OFF + N;      // N ints   : CSR row starts
constexpr int WPOS_OFF = WOFF_OFF + N;      // N ints   : scatter cursors
constexpr int ADJ_OFF  = WPOS_OFF + N;      // E ints   : CSR src ids
constexpr int BSUM_OFF = ADJ_OFF + E;       // 256 ints : scan block sums
constexpr int BSC_OFF  = BSUM_OFF + 256;    // 256 ints : scanned block sums
constexpr int SH_OFF   = BSC_OFF + 256;     // H floats
constexpr int SHW_OFF  = SH_OFF + H;        // H floats

// zero cnt+wsum (contiguous 2N) and S_h+S_hw (contiguous 2H)
__global__ __launch_bounds__(256) void k_zero(float* __restrict__ ws) {
  int tid = blockIdx.x * blockDim.x + threadIdx.x;
  if (tid < 2 * N) ws[CNT_OFF + tid] = 0.0f;  // int 0 == float 0 bits
  if (tid < 2 * H) ws[SH_OFF + tid] = 0.0f;
}

__global__ __launch_bounds__(256) void k_hist(
    const int* __restrict__ ei, int* __restrict__ cnt) {
  int e = blockIdx.x * blockDim.x + threadIdx.x;
  if (e < E) atomicAdd(&cnt[ei[E + e]], 1);
}

// block-level exclusive scan of cnt -> woff (partial), block totals -> bsum
__global__ __launch_bounds__(SCAN_B) void k_scan1(
    const int* __restrict__ cnt, int* __restrict__ woff, int* __restrict__ bsum) {
  __shared__ int s[SCAN_B];
  const int t = threadIdx.x;
  const int i = blockIdx.x * SCAN_B + t;
  const int v = (i < N) ? cnt[i] : 0;
  s[t] = v;
  __syncthreads();
  for (int off = 1; off < SCAN_B; off <<= 1) {
    int u = (t >= off) ? s[t - off] : 0;
    __syncthreads();
    s[t] += u;
    __syncthreads();
  }
  if (i < N) woff[i] = s[t] - v;
  if (t == SCAN_B - 1) bsum[blockIdx.x] = s[t];
}

__global__ __launch_bounds__(SCAN_B) void k_scan2(
    const int* __restrict__ bsum, int* __restrict__ bscan) {
  __shared__ int s[SCAN_B];
  const int t = threadIdx.x;
  const int v = (t < NBLK_SCAN) ? bsum[t] : 0;
  s[t] = v;
  __syncthreads();
  for (int off = 1; off < SCAN_B; off <<= 1) {
    int u = (t >= off) ? s[t - off] : 0;
    __syncthreads();
    s[t] += u;
    __syncthreads();
  }
  if (t < NBLK_SCAN) bscan[t] = s[t] - v;
}

__global__ __launch_bounds__(SCAN_B) void k_scan3(
    int* __restrict__ woff, const int* __restrict__ bscan, int* __restrict__ wpos) {
  const int i = blockIdx.x * SCAN_B + threadIdx.x;
  if (i < N) {
    int w = woff[i] + bscan[blockIdx.x];
    woff[i] = w;
    wpos[i] = w;
  }
}

// scatter src-ids into CSR; fused wsum[src] += 1/max(cnt[dst],1)
__global__ __launch_bounds__(256) void k_scatter(
    const int* __restrict__ ei, const int* __restrict__ cnt,
    int* __restrict__ wpos, int* __restrict__ adj, float* __restrict__ wsum) {
  int e = blockIdx.x * blockDim.x + threadIdx.x;
  if (e >= E) return;
  const int s = ei[e];
  const int d = ei[E + e];
  const int pos = atomicAdd(&wpos[d], 1);
  adj[pos] = s;
  const int c = cnt[d];
  atomicAdd(&wsum[s], 1.0f / (float)(c > 0 ? c : 1));
}

// Fused gather + layer-1 transform + global reduction.
// Phase 1 (lane=feature): wave wv gathers nodes {wv, wv+4, wv+8, wv+12} of
// the tile: coalesced adj read, broadcast x-row gathers (L2/L3), mean and
// own-x rows staged to LDS.
// Phase 2 (lane=j): waves 0-1 transform tile nodes 0-7 with j=tid&127,
// waves 2-3 nodes 8-15. LDS broadcast ds_read_b128, weights static in VGPRs,
// S_h/S_hw accumulate in registers; 2 atomics per thread at kernel end.
__global__ __launch_bounds__(256) void k_fused(
    const float* __restrict__ x, const int* __restrict__ adj,
    const int* __restrict__ cnt, const int* __restrict__ woff,
    const float* __restrict__ wsum,
    const float* __restrict__ W1l, const float* __restrict__ b1,
    const float* __restrict__ W1r,
    float* __restrict__ S_h, float* __restrict__ S_hw) {
  __shared__ float sm[TN][F];  // neighbor means
  __shared__ float sx[TN][F];  // own x rows
  const int tid = threadIdx.x;
  const int lane = tid & 63;
  const int wv = tid >> 6;      // 0..3
  const int j = tid & 127;      // hidden unit (phase 2)
  const int half = tid >> 7;    // 0: nodes 0-7, 1: nodes 8-15

  // weight rows -> VGPRs (static indexing only)
  float wl[F], wr[F];
  {
    const float4* wlp = reinterpret_cast<const float4*>(W1l + j * F);
    const float4* wrp = reinterpret_cast<const float4*>(W1r + j * F);
    #pragma unroll
    for (int i = 0; i < F / 4; ++i) {
      float4 t = wlp[i];
      wl[4 * i] = t.x; wl[4 * i + 1] = t.y; wl[4 * i + 2] = t.z; wl[4 * i + 3] = t.w;
      float4 u = wrp[i];
      wr[4 * i] = u.x; wr[4 * i + 1] = u.y; wr[4 * i + 2] = u.z; wr[4 * i + 3] = u.w;
    }
  }
  const float b1j = b1[j];

  float accS = 0.f, accW = 0.f;

  for (int t = blockIdx.x; t < NT; t += NWG_F) {
    const int nbase = t * TN;
    __syncthreads();  // previous tile's transform done before LDS overwrite

    // ---- phase 1: gather ----
    #pragma unroll
    for (int q = 0; q < 4; ++q) {
      const int ln = wv + 4 * q;
      const int n = nbase + ln;
      const int deg = cnt[n];
      const int start = woff[n];
      float acc = 0.f;
      for (int base = 0; base < deg; base += 64) {
        const int rem = deg - base;
        const int mm = rem < 64 ? rem : 64;
        const int sl = (lane < mm) ? adj[start + base + lane] : 0;
        int i = 0;
        for (; i + 3 < mm; i += 4) {
          const int s0 = __shfl(sl, i, 64);
          const int s1 = __shfl(sl, i + 1, 64);
          const int s2 = __shfl(sl, i + 2, 64);
          const int s3 = __shfl(sl, i + 3, 64);
          const float v0 = x[s0 * F + lane];
          const float v1 = x[s1 * F + lane];
          const float v2 = x[s2 * F + lane];
          const float v3 = x[s3 * F + lane];
          acc += v0; acc += v1; acc += v2; acc += v3;
        }
        for (; i < mm; ++i) {
          const int s0 = __shfl(sl, i, 64);
          acc += x[s0 * F + lane];
        }
      }
      sm[ln][lane] = acc / (float)(deg > 0 ? deg : 1);
      sx[ln][lane] = x[n * F + lane];
    }
    __syncthreads();

    // ---- phase 2: transform ----
    #pragma unroll
    for (int q = 0; q < 8; ++q) {
      const int ln = half * 8 + q;
      const int n = nbase + ln;
      const float4* mp = reinterpret_cast<const float4*>(&sm[ln][0]);
      const float4* xp = reinterpret_cast<const float4*>(&sx[ln][0]);
      float zl0 = 0.f, zl1 = 0.f, zr0 = 0.f, zr1 = 0.f;
      #pragma unroll
      for (int i = 0; i < F / 4; ++i) {
        float4 av = mp[i];  // wave-uniform -> LDS broadcast
        float4 xv = xp[i];
        zl0 = fmaf(wl[4 * i + 0], av.x, zl0);
        zl1 = fmaf(wl[4 * i + 1], av.y, zl1);
        zl0 = fmaf(wl[4 * i + 2], av.z, zl0);
        zl1 = fmaf(wl[4 * i + 3], av.w, zl1);
        zr0 = fmaf(wr[4 * i + 0], xv.x, zr0);
        zr1 = fmaf(wr[4 * i + 1], xv.y, zr1);
        zr0 = fmaf(wr[4 * i + 2], xv.z, zr0);
        zr1 = fmaf(wr[4 * i + 3], xv.w, zr1);
      }
      const float h = fmaxf((zl0 + zl1) + b1j + (zr0 + zr1), 0.0f);
      accS += h;
      accW = fmaf(wsum[n], h, accW);
    }
  }

  atomicAdd(&S_h[j], accS);
  atomicAdd(&S_hw[j], accW);
}

__global__ __launch_bounds__(64) void k_final(
    const float* __restrict__ S_h, const float* __restrict__ S_hw,
    const float* __restrict__ W2l, const float* __restrict__ b2,
    const float* __restrict__ W2r, float* __restrict__ out) {
  const int j = threadIdx.x;
  if (j < O) {
    float acc = (float)N * b2[j];
    #pragma unroll 8
    for (int k = 0; k < H; ++k)
      acc += S_hw[k] * W2l[j * H + k] + S_h[k] * W2r[j * H + k];
    out[j] = acc;
  }
}

extern "C" void kernel_launch(void* const* d_in, const int* in_sizes, int n_in,
                              void* d_out, int out_size, void* d_ws, size_t ws_size,
                              hipStream_t stream) {
  const float* x   = (const float*)d_in[0];
  const int*   ei  = (const int*)d_in[1];
  const float* W1l = (const float*)d_in[2];
  const float* b1  = (const float*)d_in[3];
  const float* W1r = (const float*)d_in[4];
  const float* W2l = (const float*)d_in[5];
  const float* b2  = (const float*)d_in[6];
  const float* W2r = (const float*)d_in[7];
  float* out = (float*)d_out;
  float* ws  = (float*)d_ws;

  int*   cnt   = (int*)(ws + CNT_OFF);
  float* wsum  = ws + WSUM_OFF;
  int*   woff  = (int*)(ws + WOFF_OFF);
  int*   wpos  = (int*)(ws + WPOS_OFF);
  int*   adj   = (int*)(ws + ADJ_OFF);
  int*   bsum  = (int*)(ws + BSUM_OFF);
  int*   bscan = (int*)(ws + BSC_OFF);
  float* S_h   = ws + SH_OFF;
  float* S_hw  = ws + SHW_OFF;

  hipLaunchKernelGGL(k_zero, dim3((2 * N + 255) / 256), dim3(256), 0, stream, ws);
  hipLaunchKernelGGL(k_hist, dim3((E + 255) / 256), dim3(256), 0, stream, ei, cnt);
  hipLaunchKernelGGL(k_scan1, dim3(NBLK_SCAN), dim3(SCAN_B), 0, stream, cnt, woff, bsum);
  hipLaunchKernelGGL(k_scan2, dim3(1), dim3(SCAN_B), 0, stream, bsum, bscan);
  hipLaunchKernelGGL(k_scan3, dim3(NBLK_SCAN), dim3(SCAN_B), 0, stream, woff, bscan, wpos);
  hipLaunchKernelGGL(k_scatter, dim3((E + 255) / 256), dim3(256), 0, stream,
                     ei, cnt, wpos, adj, wsum);
  hipLaunchKernelGGL(k_fused, dim3(NWG_F), dim3(256), 0, stream,
                     x, adj, cnt, woff, wsum, W1l, b1, W1r, S_h, S_hw);
  hipLaunchKernelGGL(k_final, dim3(1), dim3(64), 0, stream,
                     S_h, S_hw, W2l, b2, W2r, out);
}

// Round 5
// 199.105 us; speedup vs baseline: 1.4512x; 1.4512x over previous
//
#include <hip/hip_runtime.h>

// GNN_44306882625625: 2-layer SAGEConv + node-sum readout, fp32.
// out = S_hw @ W2l^T + N*b2 + S_h @ W2r^T, with S_h = sum_n h[n],
// S_hw = sum_n wsum[n]*h[n], wsum[n] = sum_{e: src=n} 1/max(cnt[dst_e],1).
// Pipeline: CSR build (hist/scan/scatter) -> k_gather (mean1, scalar-load
// adjacency) -> k_trans (register-tiled GEMM, ReLU + reduction fused).

constexpr int N = 50000;   // nodes
constexpr int F = 64;      // in feat
constexpr int H = 128;     // hidden
constexpr int O = 10;      // out
constexpr int E = 800000;  // edges

constexpr int SCAN_B = 256;
constexpr int NBLK_SCAN = (N + SCAN_B - 1) / SCAN_B;  // 196

constexpr int NTILE = (N + 63) / 64;   // 782 node tiles in k_trans
constexpr int NB_TRANS = 512;          // k_trans grid (even: j-half = parity)

// workspace layout (4-byte element offsets)
constexpr int MEAN_OFF = 0;                 // N*F floats : mean1
constexpr int CNT_OFF  = MEAN_OFF + N * F;  // N ints     : in-degree
constexpr int WSUM_OFF = CNT_OFF + N;       // N floats   : wsum
constexpr int WOFF_OFF = WSUM_OFF + N;      // N ints     : CSR row starts
constexpr int WPOS_OFF = WOFF_OFF + N;      // N ints     : scatter cursors
constexpr int ADJ_OFF  = WPOS_OFF + N;      // E ints     : CSR src ids
constexpr int BSUM_OFF = ADJ_OFF + E;       // 256 ints   : scan block sums
constexpr int BSC_OFF  = BSUM_OFF + 256;    // 256 ints   : scanned block sums
constexpr int SH_OFF   = BSC_OFF + 256;     // H floats
constexpr int SHW_OFF  = SH_OFF + H;        // H floats

__global__ __launch_bounds__(256) void k_zero(float* __restrict__ ws) {
  int tid = blockIdx.x * blockDim.x + threadIdx.x;
  if (tid < 2 * N) ws[CNT_OFF + tid] = 0.0f;  // cnt+wsum (int 0 == float 0)
  if (tid < 2 * H) ws[SH_OFF + tid] = 0.0f;   // S_h + S_hw
}

__global__ __launch_bounds__(256) void k_hist(
    const int* __restrict__ ei, int* __restrict__ cnt) {
  int e = blockIdx.x * blockDim.x + threadIdx.x;
  if (e < E) atomicAdd(&cnt[ei[E + e]], 1);
}

__global__ __launch_bounds__(SCAN_B) void k_scan1(
    const int* __restrict__ cnt, int* __restrict__ woff, int* __restrict__ bsum) {
  __shared__ int s[SCAN_B];
  const int t = threadIdx.x;
  const int i = blockIdx.x * SCAN_B + t;
  const int v = (i < N) ? cnt[i] : 0;
  s[t] = v;
  __syncthreads();
  for (int off = 1; off < SCAN_B; off <<= 1) {
    int u = (t >= off) ? s[t - off] : 0;
    __syncthreads();
    s[t] += u;
    __syncthreads();
  }
  if (i < N) woff[i] = s[t] - v;
  if (t == SCAN_B - 1) bsum[blockIdx.x] = s[t];
}

__global__ __launch_bounds__(SCAN_B) void k_scan2(
    const int* __restrict__ bsum, int* __restrict__ bscan) {
  __shared__ int s[SCAN_B];
  const int t = threadIdx.x;
  const int v = (t < NBLK_SCAN) ? bsum[t] : 0;
  s[t] = v;
  __syncthreads();
  for (int off = 1; off < SCAN_B; off <<= 1) {
    int u = (t >= off) ? s[t - off] : 0;
    __syncthreads();
    s[t] += u;
    __syncthreads();
  }
  if (t < NBLK_SCAN) bscan[t] = s[t] - v;
}

__global__ __launch_bounds__(SCAN_B) void k_scan3(
    int* __restrict__ woff, const int* __restrict__ bscan, int* __restrict__ wpos) {
  const int i = blockIdx.x * SCAN_B + threadIdx.x;
  if (i < N) {
    int w = woff[i] + bscan[blockIdx.x];
    woff[i] = w;
    wpos[i] = w;
  }
}

__global__ __launch_bounds__(256) void k_scatter(
    const int* __restrict__ ei, const int* __restrict__ cnt,
    int* __restrict__ wpos, int* __restrict__ adj, float* __restrict__ wsum) {
  int e = blockIdx.x * blockDim.x + threadIdx.x;
  if (e >= E) return;
  const int s = ei[e];
  const int d = ei[E + e];
  const int pos = atomicAdd(&wpos[d], 1);
  adj[pos] = s;
  const int c = cnt[d];
  atomicAdd(&wsum[s], 1.0f / (float)(c > 0 ? c : 1));
}

// One wave per dst node. Node id / degree / row start / adjacency are all
// wave-uniform -> scalar loads (no shfl chain). 8 independent row-gathers in
// flight; lane = feature (coalesced 256B per row read, x is L2/L3-resident).
__global__ __launch_bounds__(256) void k_gather(
    const float* __restrict__ x, const int* __restrict__ adj,
    const int* __restrict__ cnt, const int* __restrict__ woff,
    float* __restrict__ mean1) {
  const int lane = threadIdx.x & 63;
  const int wid = (blockIdx.x * blockDim.x + threadIdx.x) >> 6;
  const int n = __builtin_amdgcn_readfirstlane(wid);  // force wave-uniform
  const int deg = cnt[n];     // scalar load
  const int start = woff[n];  // scalar load
  float acc = 0.f;
  int i = 0;
  for (; i + 8 <= deg; i += 8) {
    const int s0 = adj[start + i + 0];
    const int s1 = adj[start + i + 1];
    const int s2 = adj[start + i + 2];
    const int s3 = adj[start + i + 3];
    const int s4 = adj[start + i + 4];
    const int s5 = adj[start + i + 5];
    const int s6 = adj[start + i + 6];
    const int s7 = adj[start + i + 7];
    const float v0 = x[(size_t)s0 * F + lane];
    const float v1 = x[(size_t)s1 * F + lane];
    const float v2 = x[(size_t)s2 * F + lane];
    const float v3 = x[(size_t)s3 * F + lane];
    const float v4 = x[(size_t)s4 * F + lane];
    const float v5 = x[(size_t)s5 * F + lane];
    const float v6 = x[(size_t)s6 * F + lane];
    const float v7 = x[(size_t)s7 * F + lane];
    acc += ((v0 + v1) + (v2 + v3)) + ((v4 + v5) + (v6 + v7));
  }
  for (; i < deg; ++i)
    acc += x[(size_t)adj[start + i] * F + lane];
  mean1[(size_t)n * F + lane] = acc * (deg > 0 ? 1.0f / (float)deg : 0.0f);
}

// Register-tiled GEMM: [64-node tile] x [64-j half] per block iteration.
// feat[n][0..63]=mean1 row, [64..127]=x row (LDS 32KB, pitch 128).
// wB[k][jj] = W1{l,r}^T slice for this block's j-half (LDS 32KB, loaded once;
// reads contiguous in j -> conflict-free). Thread (tm,tj) = 4 nodes x 4 j,
// 8 ds_read_b128 feed 64 FMAs per k4 step. ReLU + S_h/S_hw reduction fused;
// per-thread accumulators, one LDS reduce + 64 atomics per block at the end.
__global__ __launch_bounds__(256) void k_trans(
    const float* __restrict__ x, const float* __restrict__ mean1,
    const float* __restrict__ wsum,
    const float* __restrict__ W1l, const float* __restrict__ b1,
    const float* __restrict__ W1r,
    float* __restrict__ S_h, float* __restrict__ S_hw) {
  __shared__ float smem[16384];       // 64KB: feat[64*128] | wB[128*64]
  float* feat = smem;
  float* wB = smem + 8192;
  const int tid = threadIdx.x;
  const int jhalf = blockIdx.x & 1;
  const int jbase = jhalf * 64;
  const int tm = tid >> 4;            // 0..15 node group (4 nodes)
  const int tj = tid & 15;            // 0..15 j group (4 j)

  // load this j-half's weights, transposed: wB[k][jj], k<64 = W1l, k>=64 = W1r
  #pragma unroll
  for (int u = 0; u < 4; ++u) {
    const int idx = u * 256 + tid;    // 0..1023
    const int jj = idx >> 4;          // 0..63
    const int k4 = idx & 15;          // 0..15
    const float4 vl = *reinterpret_cast<const float4*>(&W1l[(jbase + jj) * F + k4 * 4]);
    const float4 vr = *reinterpret_cast<const float4*>(&W1r[(jbase + jj) * F + k4 * 4]);
    wB[(k4 * 4 + 0) * 64 + jj] = vl.x;
    wB[(k4 * 4 + 1) * 64 + jj] = vl.y;
    wB[(k4 * 4 + 2) * 64 + jj] = vl.z;
    wB[(k4 * 4 + 3) * 64 + jj] = vl.w;
    wB[(64 + k4 * 4 + 0) * 64 + jj] = vr.x;
    wB[(64 + k4 * 4 + 1) * 64 + jj] = vr.y;
    wB[(64 + k4 * 4 + 2) * 64 + jj] = vr.z;
    wB[(64 + k4 * 4 + 3) * 64 + jj] = vr.w;
  }
  const float4 b1v = *reinterpret_cast<const float4*>(&b1[jbase + tj * 4]);

  float accS0 = 0.f, accS1 = 0.f, accS2 = 0.f, accS3 = 0.f;
  float accW0 = 0.f, accW1 = 0.f, accW2 = 0.f, accW3 = 0.f;

  for (int t = (blockIdx.x >> 1); t < NTILE; t += (NB_TRANS >> 1)) {
    const int nbase = t * 64;
    __syncthreads();  // prev tile's reads done (also orders wB writes, 1st iter)

    // stage feat = [mean1 | x] rows, zero-padded past N
    #pragma unroll
    for (int u = 0; u < 8; ++u) {
      const int idx = u * 256 + tid;  // 0..2047
      const int nn = idx >> 5;        // 0..63
      const int q = idx & 31;         // 0..31 float4 slot
      const int gn = nbase + nn;
      float4 v = make_float4(0.f, 0.f, 0.f, 0.f);
      if (gn < N) {
        v = (q < 16)
            ? reinterpret_cast<const float4*>(mean1 + (size_t)gn * F)[q]
            : reinterpret_cast<const float4*>(x + (size_t)gn * F)[q - 16];
      }
      *reinterpret_cast<float4*>(&feat[nn * 128 + q * 4]) = v;
    }
    __syncthreads();

    float acc[4][4] = {{0.f}};
    #pragma unroll 2
    for (int k4 = 0; k4 < 32; ++k4) {
      float4 A[4], B[4];
      #pragma unroll
      for (int r = 0; r < 4; ++r)
        A[r] = *reinterpret_cast<const float4*>(&feat[(tm * 4 + r) * 128 + k4 * 4]);
      #pragma unroll
      for (int kk = 0; kk < 4; ++kk)
        B[kk] = *reinterpret_cast<const float4*>(&wB[(k4 * 4 + kk) * 64 + tj * 4]);
      #pragma unroll
      for (int r = 0; r < 4; ++r) {
        acc[r][0] = fmaf(A[r].x, B[0].x, acc[r][0]);
        acc[r][0] = fmaf(A[r].y, B[1].x, acc[r][0]);
        acc[r][0] = fmaf(A[r].z, B[2].x, acc[r][0]);
        acc[r][0] = fmaf(A[r].w, B[3].x, acc[r][0]);
        acc[r][1] = fmaf(A[r].x, B[0].y, acc[r][1]);
        acc[r][1] = fmaf(A[r].y, B[1].y, acc[r][1]);
        acc[r][1] = fmaf(A[r].z, B[2].y, acc[r][1]);
        acc[r][1] = fmaf(A[r].w, B[3].y, acc[r][1]);
        acc[r][2] = fmaf(A[r].x, B[0].z, acc[r][2]);
        acc[r][2] = fmaf(A[r].y, B[1].z, acc[r][2]);
        acc[r][2] = fmaf(A[r].z, B[2].z, acc[r][2]);
        acc[r][2] = fmaf(A[r].w, B[3].z, acc[r][2]);
        acc[r][3] = fmaf(A[r].x, B[0].w, acc[r][3]);
        acc[r][3] = fmaf(A[r].y, B[1].w, acc[r][3]);
        acc[r][3] = fmaf(A[r].z, B[2].w, acc[r][3]);
        acc[r][3] = fmaf(A[r].w, B[3].w, acc[r][3]);
      }
    }

    // fused ReLU + reduction epilogue (mask tail nodes past N)
    #pragma unroll
    for (int r = 0; r < 4; ++r) {
      const int gn = nbase + tm * 4 + r;
      const bool valid = (gn < N);
      const float wsn = valid ? wsum[gn] : 0.f;
      float h0 = valid ? fmaxf(acc[r][0] + b1v.x, 0.f) : 0.f;
      float h1 = valid ? fmaxf(acc[r][1] + b1v.y, 0.f) : 0.f;
      float h2 = valid ? fmaxf(acc[r][2] + b1v.z, 0.f) : 0.f;
      float h3 = valid ? fmaxf(acc[r][3] + b1v.w, 0.f) : 0.f;
      accS0 += h0; accS1 += h1; accS2 += h2; accS3 += h3;
      accW0 = fmaf(wsn, h0, accW0);
      accW1 = fmaf(wsn, h1, accW1);
      accW2 = fmaf(wsn, h2, accW2);
      accW3 = fmaf(wsn, h3, accW3);
    }
  }

  // block reduction over tm groups (reuse feat LDS), then 64+64 atomics
  __syncthreads();
  float* redS = smem;          // [16][64]
  float* redW = smem + 1024;   // [16][64]
  redS[tm * 64 + tj * 4 + 0] = accS0;
  redS[tm * 64 + tj * 4 + 1] = accS1;
  redS[tm * 64 + tj * 4 + 2] = accS2;
  redS[tm * 64 + tj * 4 + 3] = accS3;
  redW[tm * 64 + tj * 4 + 0] = accW0;
  redW[tm * 64 + tj * 4 + 1] = accW1;
  redW[tm * 64 + tj * 4 + 2] = accW2;
  redW[tm * 64 + tj * 4 + 3] = accW3;
  __syncthreads();
  if (tid < 64) {
    float s = 0.f, w = 0.f;
    #pragma unroll
    for (int m = 0; m < 16; ++m) {
      s += redS[m * 64 + tid];
      w += redW[m * 64 + tid];
    }
    atomicAdd(&S_h[jbase + tid], s);
    atomicAdd(&S_hw[jbase + tid], w);
  }
}

__global__ __launch_bounds__(64) void k_final(
    const float* __restrict__ S_h, const float* __restrict__ S_hw,
    const float* __restrict__ W2l, const float* __restrict__ b2,
    const float* __restrict__ W2r, float* __restrict__ out) {
  const int j = threadIdx.x;
  if (j < O) {
    float acc = (float)N * b2[j];
    #pragma unroll 8
    for (int k = 0; k < H; ++k)
      acc += S_hw[k] * W2l[j * H + k] + S_h[k] * W2r[j * H + k];
    out[j] = acc;
  }
}

extern "C" void kernel_launch(void* const* d_in, const int* in_sizes, int n_in,
                              void* d_out, int out_size, void* d_ws, size_t ws_size,
                              hipStream_t stream) {
  const float* x   = (const float*)d_in[0];
  const int*   ei  = (const int*)d_in[1];
  const float* W1l = (const float*)d_in[2];
  const float* b1  = (const float*)d_in[3];
  const float* W1r = (const float*)d_in[4];
  const float* W2l = (const float*)d_in[5];
  const float* b2  = (const float*)d_in[6];
  const float* W2r = (const float*)d_in[7];
  float* out = (float*)d_out;
  float* ws  = (float*)d_ws;

  float* mean1 = ws + MEAN_OFF;
  int*   cnt   = (int*)(ws + CNT_OFF);
  float* wsum  = ws + WSUM_OFF;
  int*   woff  = (int*)(ws + WOFF_OFF);
  int*   wpos  = (int*)(ws + WPOS_OFF);
  int*   adj   = (int*)(ws + ADJ_OFF);
  int*   bsum  = (int*)(ws + BSUM_OFF);
  int*   bscan = (int*)(ws + BSC_OFF);
  float* S_h   = ws + SH_OFF;
  float* S_hw  = ws + SHW_OFF;

  hipLaunchKernelGGL(k_zero, dim3((2 * N + 255) / 256), dim3(256), 0, stream, ws);
  hipLaunchKernelGGL(k_hist, dim3((E + 255) / 256), dim3(256), 0, stream, ei, cnt);
  hipLaunchKernelGGL(k_scan1, dim3(NBLK_SCAN), dim3(SCAN_B), 0, stream, cnt, woff, bsum);
  hipLaunchKernelGGL(k_scan2, dim3(1), dim3(SCAN_B), 0, stream, bsum, bscan);
  hipLaunchKernelGGL(k_scan3, dim3(NBLK_SCAN), dim3(SCAN_B), 0, stream, woff, bscan, wpos);
  hipLaunchKernelGGL(k_scatter, dim3((E + 255) / 256), dim3(256), 0, stream,
                     ei, cnt, wpos, adj, wsum);
  hipLaunchKernelGGL(k_gather, dim3(N / 4), dim3(256), 0, stream,
                     x, adj, cnt, woff, mean1);
  hipLaunchKernelGGL(k_trans, dim3(NB_TRANS), dim3(256), 0, stream,
                     x, mean1, wsum, W1l, b1, W1r, S_h, S_hw);
  hipLaunchKernelGGL(k_final, dim3(1), dim3(64), 0, stream,
                     S_h, S_hw, W2l, b2, W2r, out);
}